// Round 9
// baseline (295.919 us; speedup 1.0000x reference)
//
#include <hip/hip_runtime.h>
#include <hip/hip_bf16.h>

#define NT 4096      // tokens
#define DIM 768
#define NE 1536      // experts
#define ED 64        // expert dim
#define GAP_THR 8e-3f

typedef __attribute__((ext_vector_type(8))) short short8v;
typedef __attribute__((ext_vector_type(4))) float f32x4;

__device__ __forceinline__ unsigned short f2bf(float f) {
  unsigned int u = __float_as_uint(f);
  unsigned int r = (u + 0x7fffu + ((u >> 16) & 1u)) >> 16;   // RNE
  return (unsigned short)r;
}
__device__ __forceinline__ float bf2f(unsigned short h) {
  return __uint_as_float(((unsigned int)h) << 16);
}

__device__ __forceinline__ void gload16(const void* g, void* l) {
  __builtin_amdgcn_global_load_lds((const __attribute__((address_space(1))) void*)g,
                                   (__attribute__((address_space(3))) void*)l, 16, 0, 0);
}

__device__ __forceinline__ void top2_merge(float& m1, int& i1, float& m2, int& i2,
                                           float om1, int oi1, float om2, int oi2) {
  if (om1 > m1 || (om1 == m1 && oi1 < i1)) {
    if (m1 > om2 || (m1 == om2 && i1 < oi2)) { m2 = m1; i2 = i1; }
    else { m2 = om2; i2 = oi2; }
    m1 = om1; i1 = oi1;
  } else {
    if (om1 > m2 || (om1 == m2 && oi1 < i2)) { m2 = om1; i2 = oi1; }
  }
}

// ---- Kernel 0: fp32 -> (bf16 hi, bf16 lo) split (x and gate_w); zero rc_cnt ----
__global__ __launch_bounds__(256) void split_all(
    const float* __restrict__ x, const float* __restrict__ gw,
    unsigned short* __restrict__ xhi, unsigned short* __restrict__ xlo,
    unsigned short* __restrict__ ghi, unsigned short* __restrict__ glo,
    int* __restrict__ rc_cnt) {
  if (blockIdx.x == 0 && threadIdx.x == 0) *rc_cnt = 0;
  const int nx4 = NT * DIM / 4;
  const int ng4 = NE * DIM / 4;
  int i = blockIdx.x * 256 + threadIdx.x;
  const float* src; unsigned short* hi; unsigned short* lo; int j;
  if (i < nx4) { src = x; hi = xhi; lo = xlo; j = i; }
  else { j = i - nx4; if (j >= ng4) return; src = gw; hi = ghi; lo = glo; }
  float4 v = ((const float4*)src)[j];
  unsigned short h0 = f2bf(v.x), h1 = f2bf(v.y), h2 = f2bf(v.z), h3 = f2bf(v.w);
  ((ushort4*)hi)[j] = make_ushort4(h0, h1, h2, h3);
  ((ushort4*)lo)[j] = make_ushort4(f2bf(v.x - bf2f(h0)), f2bf(v.y - bf2f(h1)),
                                   f2bf(v.z - bf2f(h2)), f2bf(v.w - bf2f(h3)));
}

// ---- Kernel 1: gating GEMM (bf16x3 MFMA) + fused partial softmax ----
__global__ __launch_bounds__(256) void gate_mfma(
    const unsigned short* __restrict__ xhi, const unsigned short* __restrict__ xlo,
    const unsigned short* __restrict__ ghi, const unsigned short* __restrict__ glo,
    const float* __restrict__ gb, const float* __restrict__ noise,
    float4* __restrict__ part_a, int* __restrict__ part_i2) {
  __shared__ __align__(16) unsigned short sA[2 * 128 * 32];  // [0..4095]=hi, [4096..]=lo
  __shared__ __align__(16) unsigned short sB[2 * 128 * 32];
  const int tid = threadIdx.x;
  const int w = tid >> 6, lane = tid & 63;
  const int wr = w >> 1, wc = w & 1;
  const int bm = blockIdx.x, bn = blockIdx.y;
  const int fr = lane & 15;
  const int fg = lane >> 4;
  const int gsw = fg ^ ((fr >> 1) & 3);

  f32x4 acc[4][4];
#pragma unroll
  for (int i = 0; i < 4; i++)
#pragma unroll
    for (int j = 0; j < 4; j++) acc[i][j] = (f32x4){0.f, 0.f, 0.f, 0.f};

  const size_t arow = (size_t)bm * 128 * DIM;
  const size_t brow = (size_t)bn * 128 * DIM;
  const int sr_lo = tid >> 2;
  const int sg = (tid & 3) ^ ((tid >> 3) & 3);   // pre-swizzled source granule

  for (int kt = 0; kt < DIM; kt += 32) {
    __syncthreads();
#pragma unroll
    for (int h = 0; h < 2; h++) {
      const int r = h * 64 + sr_lo;
      const size_t asrc = arow + (size_t)r * DIM + kt + sg * 8;
      const size_t bsrc = brow + (size_t)r * DIM + kt + sg * 8;
      const int dofs = h * 2048 + w * 512;
      gload16(xhi + asrc, &sA[dofs]);
      gload16(xlo + asrc, &sA[4096 + dofs]);
      gload16(ghi + bsrc, &sB[dofs]);
      gload16(glo + bsrc, &sB[4096 + dofs]);
    }
    __syncthreads();

    short8v ah[4], al[4], bh[4], bl[4];
#pragma unroll
    for (int mf = 0; mf < 4; mf++) {
      int ro = (wr * 64 + mf * 16 + fr) * 32 + gsw * 8;
      ah[mf] = *(const short8v*)&sA[ro];
      al[mf] = *(const short8v*)&sA[4096 + ro];
    }
#pragma unroll
    for (int nf = 0; nf < 4; nf++) {
      int ro = (wc * 64 + nf * 16 + fr) * 32 + gsw * 8;
      bh[nf] = *(const short8v*)&sB[ro];
      bl[nf] = *(const short8v*)&sB[4096 + ro];
    }
#pragma unroll
    for (int mf = 0; mf < 4; mf++)
#pragma unroll
      for (int nf = 0; nf < 4; nf++) {
        f32x4 c = acc[mf][nf];
        c = __builtin_amdgcn_mfma_f32_16x16x32_bf16(ah[mf], bh[nf], c, 0, 0, 0);
        c = __builtin_amdgcn_mfma_f32_16x16x32_bf16(ah[mf], bl[nf], c, 0, 0, 0);
        c = __builtin_amdgcn_mfma_f32_16x16x32_bf16(al[mf], bh[nf], c, 0, 0, 0);
        acc[mf][nf] = c;
      }
  }

  // fused epilogue: bias + noise, per-token top-2 + expsum over this 64-col chunk
  const int gm0 = bm * 128 + wr * 64;
  const int gn0 = bn * 128 + wc * 64;
  const int chunk = bn * 2 + wc;   // 0..23
  int gcol[4]; float gbv[4];
#pragma unroll
  for (int nf = 0; nf < 4; nf++) { gcol[nf] = gn0 + nf * 16 + fr; gbv[nf] = gb[gcol[nf]]; }
#pragma unroll
  for (int mf = 0; mf < 4; mf++) {
    float sv[4][4];
#pragma unroll
    for (int nf = 0; nf < 4; nf++)
#pragma unroll
      for (int reg = 0; reg < 4; reg++) {
        int gm = gm0 + mf * 16 + fg * 4 + reg;
        sv[nf][reg] = acc[mf][nf][reg] + gbv[nf] + 0.1f * noise[(size_t)gm * NE + gcol[nf]];
      }
#pragma unroll
    for (int reg = 0; reg < 4; reg++) {
      float m1 = sv[0][reg]; int i1 = gcol[0];
      float m2 = -3e38f; int i2 = 0x7fffffff;
#pragma unroll
      for (int nf = 1; nf < 4; nf++) {
        float v = sv[nf][reg]; int ii = gcol[nf];
        if (v > m1 || (v == m1 && ii < i1)) { m2 = m1; i2 = i1; m1 = v; i1 = ii; }
        else if (v > m2 || (v == m2 && ii < i2)) { m2 = v; i2 = ii; }
      }
#pragma unroll
      for (int off = 1; off <= 8; off <<= 1) {
        float om1 = __shfl_xor(m1, off, 64); int oi1 = __shfl_xor(i1, off, 64);
        float om2 = __shfl_xor(m2, off, 64); int oi2 = __shfl_xor(i2, off, 64);
        top2_merge(m1, i1, m2, i2, om1, oi1, om2, oi2);
      }
      float ssum = 0.f;
#pragma unroll
      for (int nf = 0; nf < 4; nf++) ssum += __expf(sv[nf][reg] - m1);
#pragma unroll
      for (int off = 1; off <= 8; off <<= 1) ssum += __shfl_xor(ssum, off, 64);
      if (fr == 0) {
        int gm = gm0 + mf * 16 + fg * 4 + reg;
        part_a[(size_t)gm * 24 + chunk] = make_float4(m1, m2, ssum, __int_as_float(i1));
        part_i2[(size_t)gm * 24 + chunk] = i2;
      }
    }
  }
}

// ---- Kernel 2: merge 24 partials/token -> topw, idx, recheck flags ----
__global__ __launch_bounds__(256) void finalize(
    const float4* __restrict__ part_a, const int* __restrict__ part_i2,
    float* __restrict__ topw, int* __restrict__ idx,
    int* __restrict__ rc_count, int* __restrict__ rc_n, int* __restrict__ rc_i2) {
  const int wv = threadIdx.x >> 6, lane = threadIdx.x & 63;
  const int n = blockIdx.x * 4 + wv;
  float m1 = -3e38f, m2 = -3e38f, lm1 = -3e38f, lsum = 0.f;
  int i1 = 0x7fffffff, i2 = 0x7fffffff;
  if (lane < 24) {
    float4 pa = part_a[(size_t)n * 24 + lane];
    m1 = pa.x; m2 = pa.y; lsum = pa.z; i1 = __float_as_int(pa.w);
    i2 = part_i2[(size_t)n * 24 + lane];
    lm1 = pa.x;
  }
#pragma unroll
  for (int off = 1; off <= 32; off <<= 1) {
    float om1 = __shfl_xor(m1, off, 64); int oi1 = __shfl_xor(i1, off, 64);
    float om2 = __shfl_xor(m2, off, 64); int oi2 = __shfl_xor(i2, off, 64);
    top2_merge(m1, i1, m2, i2, om1, oi1, om2, oi2);
  }
  float contrib = (lane < 24) ? __expf(lm1 - m1) * lsum : 0.f;
#pragma unroll
  for (int off = 1; off <= 32; off <<= 1) contrib += __shfl_xor(contrib, off, 64);
  if (lane == 0) {
    topw[n] = 1.0f / contrib;
    idx[n] = i1;
    if (m1 - m2 < GAP_THR) {
      int p = atomicAdd(rc_count, 1);
      rc_n[p] = n; rc_i2[p] = i2;
    }
  }
}

// ---- Kernel 2b: fp32 exact recheck of near-tied top-2 (fixes idx only) ----
__global__ __launch_bounds__(256) void recheck(
    const float* __restrict__ x, const float* __restrict__ gw,
    const float* __restrict__ gb, const float* __restrict__ noise,
    const int* __restrict__ rc_n, const int* __restrict__ rc_i2,
    const int* __restrict__ rc_count, int* __restrict__ idx) {
  __shared__ float r1[4], r2[4];
  const int cnt = *rc_count;
  const int tid = threadIdx.x;
  const int w = tid >> 6, lane = tid & 63;
  for (int t = blockIdx.x; t < cnt; t += gridDim.x) {
    const int n = rc_n[t];
    const int e1 = idx[n], e2 = rc_i2[t];
    const float* xr = x + (size_t)n * DIM;
    const float* w1 = gw + (size_t)e1 * DIM;
    const float* w2 = gw + (size_t)e2 * DIM;
    float p1 = 0.f, p2 = 0.f;
    for (int k = tid; k < DIM; k += 256) {
      float xv = xr[k];
      p1 += xv * w1[k];
      p2 += xv * w2[k];
    }
#pragma unroll
    for (int off = 32; off; off >>= 1) {
      p1 += __shfl_xor(p1, off, 64);
      p2 += __shfl_xor(p2, off, 64);
    }
    if (lane == 0) { r1[w] = p1; r2[w] = p2; }
    __syncthreads();
    if (tid == 0) {
      float s1 = r1[0] + r1[1] + r1[2] + r1[3] + gb[e1] + 0.1f * noise[(size_t)n * NE + e1];
      float s2 = r2[0] + r2[1] + r2[2] + r2[3] + gb[e2] + 0.1f * noise[(size_t)n * NE + e2];
      if (s2 > s1 || (s2 == s1 && e2 < e1)) idx[n] = e2;
    }
    __syncthreads();
  }
}

// ---- Kernel 3: expert partial GEMV, 3-way d-slice, zero-barrier streaming ----
// Block (e, s): expert e, d-slice [s*256, s*256+256). W slice = [64 rows][64 f4]:
// each row is EXACTLY one coalesced 1KB wave-load. x fragments direct from
// global (L2-hot). No LDS staging, no barriers after the toklist scan. Low
// VGPR (~60) + 4608 blocks -> ~32 streaming waves/CU. Slice 0 adds eb.
__global__ __launch_bounds__(256) void expert_y(
    const float* __restrict__ x, const float* __restrict__ ew,
    const float* __restrict__ eb, const int* __restrict__ idx,
    float* __restrict__ yp) {   // yp[3][NT][ED]
  const int e = blockIdx.x, s = blockIdx.y;
  __shared__ int toklist[128];
  __shared__ int ntok_s;
  const int tid = threadIdx.x;
  const int w = tid >> 6, lane = tid & 63;

  if (tid == 0) ntok_s = 0;
  __syncthreads();
  for (int q = tid; q < NT / 4; q += 256) {
    int4 v = ((const int4*)idx)[q];
    int n0 = q * 4;
    if (v.x == e) toklist[atomicAdd(&ntok_s, 1) & 127] = n0;
    if (v.y == e) toklist[atomicAdd(&ntok_s, 1) & 127] = n0 + 1;
    if (v.z == e) toklist[atomicAdd(&ntok_s, 1) & 127] = n0 + 2;
    if (v.w == e) toklist[atomicAdd(&ntok_s, 1) & 127] = n0 + 3;
  }
  __syncthreads();
  const int cnt = min(ntok_s, 128);
  if (cnt == 0) return;

  const float4* W4 = (const float4*)(ew + (size_t)e * ED * DIM);  // [64][192] f4
  const float4* X4 = (const float4*)x;
  float* ypo = yp + (size_t)s * NT * ED;

  for (int c0 = 0; c0 < cnt; c0 += 8) {
    const int cc = min(8, cnt - c0);
    int tok_l[8];
#pragma unroll
    for (int t = 0; t < 8; t++) tok_l[t] = toklist[(c0 + t) & 127];

    // per-lane x fragment for each token: x[tok][s*256 + lane*4 .. +4)
    f32x4 xf[8];
#pragma unroll
    for (int t = 0; t < 8; t++)
      xf[t] = (t < cc) ? *(const f32x4*)&X4[(size_t)tok_l[t] * 192 + s * 64 + lane]
                       : (f32x4){0.f, 0.f, 0.f, 0.f};

    // wave w owns rows w*16..w*16+15; one coalesced 1KB load per row
    for (int a = 0; a < 16; a++) {
      const int o = w * 16 + a;
      f32x4 wv = *(const f32x4*)&W4[(size_t)o * 192 + s * 64 + lane];
      float p[8];
#pragma unroll
      for (int t = 0; t < 8; t++)
        p[t] = wv.x * xf[t].x + wv.y * xf[t].y + wv.z * xf[t].z + wv.w * xf[t].w;
      const float ebv = (s == 0) ? eb[e * ED + o] : 0.f;
#pragma unroll
      for (int t = 0; t < 8; t++) {
        if (t < cc) {
          float r = p[t];
          r += __shfl_xor(r, 1, 64);
          r += __shfl_xor(r, 2, 64);
          r += __shfl_xor(r, 4, 64);
          r += __shfl_xor(r, 8, 64);
          r += __shfl_xor(r, 16, 64);
          r += __shfl_xor(r, 32, 64);
          if (lane == 0) ypo[(size_t)tok_l[t] * ED + o] = r + ebv;
        }
      }
    }
  }
}

// ---- Kernel 4: projection + scale by top_w (sums the 3 d-slice partials) ----
__global__ __launch_bounds__(256) void proj_kernel(
    const float* __restrict__ yp, const float* __restrict__ pw,
    const float* __restrict__ pb, const float* __restrict__ topw,
    float* __restrict__ out) {
  const int b = blockIdx.x;
  const int tid = threadIdx.x;
  __shared__ float4 ys4[8 * 16];
  __shared__ float tw[8];
  const float4* yp0 = (const float4*)yp;
  const float4* yp1 = (const float4*)(yp + (size_t)NT * ED);
  const float4* yp2 = (const float4*)(yp + (size_t)2 * NT * ED);
  if (tid < 128) {
    int t = tid >> 4, q = tid & 15;
    size_t i = ((size_t)b * 8 + t) * 16 + q;
    float4 a = yp0[i], c = yp1[i], d = yp2[i];
    ys4[tid] = make_float4(a.x + c.x + d.x, a.y + c.y + d.y,
                           a.z + c.z + d.z, a.w + c.w + d.w);
  }
  if (tid < 8) tw[tid] = topw[b * 8 + tid];
  __syncthreads();
  const float4* pw4 = (const float4*)pw;
#pragma unroll
  for (int c = 0; c < 3; c++) {
    int d = c * 256 + tid;
    float4 pwv[16];
#pragma unroll
    for (int q = 0; q < 16; q++) pwv[q] = pw4[(size_t)d * 16 + q];
    float pbv = pb[d];
    for (int t = 0; t < 8; t++) {
      const float4* yv4 = &ys4[t * 16];
      float s = 0.f;
#pragma unroll
      for (int q = 0; q < 16; q++) {
        float4 yv = yv4[q];
        s += pwv[q].x * yv.x + pwv[q].y * yv.y + pwv[q].z * yv.z + pwv[q].w * yv.w;
      }
      out[((size_t)b * 8 + t) * DIM + d] = (s + pbv) * tw[t];
    }
  }
}

// ---------------- launch ----------------
extern "C" void kernel_launch(void* const* d_in, const int* in_sizes, int n_in,
                              void* d_out, int out_size, void* d_ws, size_t ws_size,
                              hipStream_t stream) {
  const float* x      = (const float*)d_in[0];
  const float* noise  = (const float*)d_in[1];
  const float* gate_w = (const float*)d_in[2];
  const float* gate_b = (const float*)d_in[3];
  const float* ew     = (const float*)d_in[4];
  const float* eb     = (const float*)d_in[5];
  const float* pw     = (const float*)d_in[6];
  const float* pb     = (const float*)d_in[7];
  float* out = (float*)d_out;

  char* ws = (char*)d_ws;
  unsigned short* xhi    = (unsigned short*)(ws);                // 6291456
  unsigned short* xlo    = (unsigned short*)(ws + 6291456);      // 6291456
  unsigned short* ghi    = (unsigned short*)(ws + 12582912);     // 2359296
  unsigned short* glo    = (unsigned short*)(ws + 14942208);     // 2359296
  float4*         part_a = (float4*)(ws + 17301504);             // 1572864
  int*            part_i2= (int*)  (ws + 18874368);              //  393216
  float*          yp     = (float*)(ws + 19267584);              // 3145728 (3 slices)
  float*          topw   = (float*)(ws + 22413312);              //   16384
  int*            idx    = (int*)  (ws + 22429696);              //   16384
  int*            rc_cnt = (int*)  (ws + 22446080);              //     256
  int*            rc_n   = (int*)  (ws + 22446336);              //   16384
  int*            rc_i2  = (int*)  (ws + 22462720);              //   16384

  split_all<<<(NT * DIM / 4 + NE * DIM / 4 + 255) / 256, 256, 0, stream>>>(
      x, gate_w, xhi, xlo, ghi, glo, rc_cnt);
  gate_mfma<<<dim3(NT / 128, NE / 128), 256, 0, stream>>>(
      xhi, xlo, ghi, glo, gate_b, noise, part_a, part_i2);
  finalize<<<NT / 4, 256, 0, stream>>>(part_a, part_i2, topw, idx,
                                       rc_cnt, rc_n, rc_i2);
  recheck<<<64, 256, 0, stream>>>(x, gate_w, gate_b, noise, rc_n, rc_i2, rc_cnt, idx);
  expert_y<<<dim3(NE, 3), 256, 0, stream>>>(x, ew, eb, idx, yp);
  proj_kernel<<<NT / 8, 256, 0, stream>>>(yp, pw, pb, topw, out);
}

// Round 10
// 246.547 us; speedup vs baseline: 1.2003x; 1.2003x over previous
//
#include <hip/hip_runtime.h>
#include <hip/hip_bf16.h>

#define NT 4096      // tokens
#define DIM 768
#define NE 1536      // experts
#define ED 64        // expert dim
#define GAP_THR 8e-3f

typedef __attribute__((ext_vector_type(8))) short short8v;
typedef __attribute__((ext_vector_type(4))) float f32x4;

__device__ __forceinline__ unsigned short f2bf(float f) {
  unsigned int u = __float_as_uint(f);
  unsigned int r = (u + 0x7fffu + ((u >> 16) & 1u)) >> 16;   // RNE
  return (unsigned short)r;
}
__device__ __forceinline__ float bf2f(unsigned short h) {
  return __uint_as_float(((unsigned int)h) << 16);
}

__device__ __forceinline__ void gload16(const void* g, void* l) {
  __builtin_amdgcn_global_load_lds((const __attribute__((address_space(1))) void*)g,
                                   (__attribute__((address_space(3))) void*)l, 16, 0, 0);
}

__device__ __forceinline__ void top2_merge(float& m1, int& i1, float& m2, int& i2,
                                           float om1, int oi1, float om2, int oi2) {
  if (om1 > m1 || (om1 == m1 && oi1 < i1)) {
    if (m1 > om2 || (m1 == om2 && i1 < oi2)) { m2 = m1; i2 = i1; }
    else { m2 = om2; i2 = oi2; }
    m1 = om1; i1 = oi1;
  } else {
    if (om1 > m2 || (om1 == m2 && oi1 < i2)) { m2 = om1; i2 = oi1; }
  }
}

// ---- Kernel 0: fp32 -> (bf16 hi, bf16 lo) split (x and gate_w); zero rc_cnt ----
__global__ __launch_bounds__(256) void split_all(
    const float* __restrict__ x, const float* __restrict__ gw,
    unsigned short* __restrict__ xhi, unsigned short* __restrict__ xlo,
    unsigned short* __restrict__ ghi, unsigned short* __restrict__ glo,
    int* __restrict__ rc_cnt) {
  if (blockIdx.x == 0 && threadIdx.x == 0) *rc_cnt = 0;
  const int nx4 = NT * DIM / 4;
  const int ng4 = NE * DIM / 4;
  int i = blockIdx.x * 256 + threadIdx.x;
  const float* src; unsigned short* hi; unsigned short* lo; int j;
  if (i < nx4) { src = x; hi = xhi; lo = xlo; j = i; }
  else { j = i - nx4; if (j >= ng4) return; src = gw; hi = ghi; lo = glo; }
  float4 v = ((const float4*)src)[j];
  unsigned short h0 = f2bf(v.x), h1 = f2bf(v.y), h2 = f2bf(v.z), h3 = f2bf(v.w);
  ((ushort4*)hi)[j] = make_ushort4(h0, h1, h2, h3);
  ((ushort4*)lo)[j] = make_ushort4(f2bf(v.x - bf2f(h0)), f2bf(v.y - bf2f(h1)),
                                   f2bf(v.z - bf2f(h2)), f2bf(v.w - bf2f(h3)));
}

// ---- Kernel 1: gating GEMM (bf16x3 MFMA) + fused partial softmax ----
__global__ __launch_bounds__(256) void gate_mfma(
    const unsigned short* __restrict__ xhi, const unsigned short* __restrict__ xlo,
    const unsigned short* __restrict__ ghi, const unsigned short* __restrict__ glo,
    const float* __restrict__ gb, const float* __restrict__ noise,
    float4* __restrict__ part_a, int* __restrict__ part_i2) {
  __shared__ __align__(16) unsigned short sA[2 * 128 * 32];  // [0..4095]=hi, [4096..]=lo
  __shared__ __align__(16) unsigned short sB[2 * 128 * 32];
  const int tid = threadIdx.x;
  const int w = tid >> 6, lane = tid & 63;
  const int wr = w >> 1, wc = w & 1;
  const int bm = blockIdx.x, bn = blockIdx.y;
  const int fr = lane & 15;
  const int fg = lane >> 4;
  const int gsw = fg ^ ((fr >> 1) & 3);

  f32x4 acc[4][4];
#pragma unroll
  for (int i = 0; i < 4; i++)
#pragma unroll
    for (int j = 0; j < 4; j++) acc[i][j] = (f32x4){0.f, 0.f, 0.f, 0.f};

  const size_t arow = (size_t)bm * 128 * DIM;
  const size_t brow = (size_t)bn * 128 * DIM;
  const int sr_lo = tid >> 2;
  const int sg = (tid & 3) ^ ((tid >> 3) & 3);   // pre-swizzled source granule

  for (int kt = 0; kt < DIM; kt += 32) {
    __syncthreads();
#pragma unroll
    for (int h = 0; h < 2; h++) {
      const int r = h * 64 + sr_lo;
      const size_t asrc = arow + (size_t)r * DIM + kt + sg * 8;
      const size_t bsrc = brow + (size_t)r * DIM + kt + sg * 8;
      const int dofs = h * 2048 + w * 512;
      gload16(xhi + asrc, &sA[dofs]);
      gload16(xlo + asrc, &sA[4096 + dofs]);
      gload16(ghi + bsrc, &sB[dofs]);
      gload16(glo + bsrc, &sB[4096 + dofs]);
    }
    __syncthreads();

    short8v ah[4], al[4], bh[4], bl[4];
#pragma unroll
    for (int mf = 0; mf < 4; mf++) {
      int ro = (wr * 64 + mf * 16 + fr) * 32 + gsw * 8;
      ah[mf] = *(const short8v*)&sA[ro];
      al[mf] = *(const short8v*)&sA[4096 + ro];
    }
#pragma unroll
    for (int nf = 0; nf < 4; nf++) {
      int ro = (wc * 64 + nf * 16 + fr) * 32 + gsw * 8;
      bh[nf] = *(const short8v*)&sB[ro];
      bl[nf] = *(const short8v*)&sB[4096 + ro];
    }
#pragma unroll
    for (int mf = 0; mf < 4; mf++)
#pragma unroll
      for (int nf = 0; nf < 4; nf++) {
        f32x4 c = acc[mf][nf];
        c = __builtin_amdgcn_mfma_f32_16x16x32_bf16(ah[mf], bh[nf], c, 0, 0, 0);
        c = __builtin_amdgcn_mfma_f32_16x16x32_bf16(ah[mf], bl[nf], c, 0, 0, 0);
        c = __builtin_amdgcn_mfma_f32_16x16x32_bf16(al[mf], bh[nf], c, 0, 0, 0);
        acc[mf][nf] = c;
      }
  }

  // fused epilogue: bias + noise, per-token top-2 + expsum over this 64-col chunk
  const int gm0 = bm * 128 + wr * 64;
  const int gn0 = bn * 128 + wc * 64;
  const int chunk = bn * 2 + wc;   // 0..23
  int gcol[4]; float gbv[4];
#pragma unroll
  for (int nf = 0; nf < 4; nf++) { gcol[nf] = gn0 + nf * 16 + fr; gbv[nf] = gb[gcol[nf]]; }
#pragma unroll
  for (int mf = 0; mf < 4; mf++) {
    float sv[4][4];
#pragma unroll
    for (int nf = 0; nf < 4; nf++)
#pragma unroll
      for (int reg = 0; reg < 4; reg++) {
        int gm = gm0 + mf * 16 + fg * 4 + reg;
        sv[nf][reg] = acc[mf][nf][reg] + gbv[nf] + 0.1f * noise[(size_t)gm * NE + gcol[nf]];
      }
#pragma unroll
    for (int reg = 0; reg < 4; reg++) {
      float m1 = sv[0][reg]; int i1 = gcol[0];
      float m2 = -3e38f; int i2 = 0x7fffffff;
#pragma unroll
      for (int nf = 1; nf < 4; nf++) {
        float v = sv[nf][reg]; int ii = gcol[nf];
        if (v > m1 || (v == m1 && ii < i1)) { m2 = m1; i2 = i1; m1 = v; i1 = ii; }
        else if (v > m2 || (v == m2 && ii < i2)) { m2 = v; i2 = ii; }
      }
#pragma unroll
      for (int off = 1; off <= 8; off <<= 1) {
        float om1 = __shfl_xor(m1, off, 64); int oi1 = __shfl_xor(i1, off, 64);
        float om2 = __shfl_xor(m2, off, 64); int oi2 = __shfl_xor(i2, off, 64);
        top2_merge(m1, i1, m2, i2, om1, oi1, om2, oi2);
      }
      float ssum = 0.f;
#pragma unroll
      for (int nf = 0; nf < 4; nf++) ssum += __expf(sv[nf][reg] - m1);
#pragma unroll
      for (int off = 1; off <= 8; off <<= 1) ssum += __shfl_xor(ssum, off, 64);
      if (fr == 0) {
        int gm = gm0 + mf * 16 + fg * 4 + reg;
        part_a[(size_t)gm * 24 + chunk] = make_float4(m1, m2, ssum, __int_as_float(i1));
        part_i2[(size_t)gm * 24 + chunk] = i2;
      }
    }
  }
}

// ---- Kernel 2: merge 24 partials/token -> topw, idx, recheck flags ----
__global__ __launch_bounds__(256) void finalize(
    const float4* __restrict__ part_a, const int* __restrict__ part_i2,
    float* __restrict__ topw, int* __restrict__ idx,
    int* __restrict__ rc_count, int* __restrict__ rc_n, int* __restrict__ rc_i2) {
  const int wv = threadIdx.x >> 6, lane = threadIdx.x & 63;
  const int n = blockIdx.x * 4 + wv;
  float m1 = -3e38f, m2 = -3e38f, lm1 = -3e38f, lsum = 0.f;
  int i1 = 0x7fffffff, i2 = 0x7fffffff;
  if (lane < 24) {
    float4 pa = part_a[(size_t)n * 24 + lane];
    m1 = pa.x; m2 = pa.y; lsum = pa.z; i1 = __float_as_int(pa.w);
    i2 = part_i2[(size_t)n * 24 + lane];
    lm1 = pa.x;
  }
#pragma unroll
  for (int off = 1; off <= 32; off <<= 1) {
    float om1 = __shfl_xor(m1, off, 64); int oi1 = __shfl_xor(i1, off, 64);
    float om2 = __shfl_xor(m2, off, 64); int oi2 = __shfl_xor(i2, off, 64);
    top2_merge(m1, i1, m2, i2, om1, oi1, om2, oi2);
  }
  float contrib = (lane < 24) ? __expf(lm1 - m1) * lsum : 0.f;
#pragma unroll
  for (int off = 1; off <= 32; off <<= 1) contrib += __shfl_xor(contrib, off, 64);
  if (lane == 0) {
    topw[n] = 1.0f / contrib;
    idx[n] = i1;
    if (m1 - m2 < GAP_THR) {
      int p = atomicAdd(rc_count, 1);
      rc_n[p] = n; rc_i2[p] = i2;
    }
  }
}

// ---- Kernel 2b: fp32 exact recheck of near-tied top-2 (fixes idx only) ----
__global__ __launch_bounds__(256) void recheck(
    const float* __restrict__ x, const float* __restrict__ gw,
    const float* __restrict__ gb, const float* __restrict__ noise,
    const int* __restrict__ rc_n, const int* __restrict__ rc_i2,
    const int* __restrict__ rc_count, int* __restrict__ idx) {
  __shared__ float r1[4], r2[4];
  const int cnt = *rc_count;
  const int tid = threadIdx.x;
  const int w = tid >> 6, lane = tid & 63;
  for (int t = blockIdx.x; t < cnt; t += gridDim.x) {
    const int n = rc_n[t];
    const int e1 = idx[n], e2 = rc_i2[t];
    const float* xr = x + (size_t)n * DIM;
    const float* w1 = gw + (size_t)e1 * DIM;
    const float* w2 = gw + (size_t)e2 * DIM;
    float p1 = 0.f, p2 = 0.f;
    for (int k = tid; k < DIM; k += 256) {
      float xv = xr[k];
      p1 += xv * w1[k];
      p2 += xv * w2[k];
    }
#pragma unroll
    for (int off = 32; off; off >>= 1) {
      p1 += __shfl_xor(p1, off, 64);
      p2 += __shfl_xor(p2, off, 64);
    }
    if (lane == 0) { r1[w] = p1; r2[w] = p2; }
    __syncthreads();
    if (tid == 0) {
      float s1 = r1[0] + r1[1] + r1[2] + r1[3] + gb[e1] + 0.1f * noise[(size_t)n * NE + e1];
      float s2 = r2[0] + r2[1] + r2[2] + r2[3] + gb[e2] + 0.1f * noise[(size_t)n * NE + e2];
      if (s2 > s1 || (s2 == s1 && e2 < e1)) idx[n] = e2;
    }
    __syncthreads();
  }
}

// ---- Kernel 3: per-expert y = x·ewT + eb, coalesced streaming, 4-token groups,
// 2-stage register prefetch, merged 4-token butterfly reduce (9 shfl/row). ----
__global__ __launch_bounds__(256) void expert_y(
    const float* __restrict__ x, const float* __restrict__ ew,
    const float* __restrict__ eb, const int* __restrict__ idx,
    float* __restrict__ y) {
  const int e = blockIdx.x;
  __shared__ int toklist[128];
  __shared__ int ntok_s;
  const int tid = threadIdx.x;
  const int w = tid >> 6, lane = tid & 63;

  if (tid == 0) ntok_s = 0;
  __syncthreads();
  for (int q = tid; q < NT / 4; q += 256) {
    int4 v = ((const int4*)idx)[q];
    int n0 = q * 4;
    if (v.x == e) toklist[atomicAdd(&ntok_s, 1) & 127] = n0;
    if (v.y == e) toklist[atomicAdd(&ntok_s, 1) & 127] = n0 + 1;
    if (v.z == e) toklist[atomicAdd(&ntok_s, 1) & 127] = n0 + 2;
    if (v.w == e) toklist[atomicAdd(&ntok_s, 1) & 127] = n0 + 3;
  }
  __syncthreads();
  const int cnt = min(ntok_s, 128);
  if (cnt == 0) return;

  const float4* W4 = (const float4*)(ew + (size_t)e * ED * DIM);  // [64][192] f4
  const float4* X4 = (const float4*)x;
  const float4* Wc = W4 + w * 16 * 192;   // wave's 16 contiguous rows

  for (int c0 = 0; c0 < cnt; c0 += 4) {
    const int cc = min(4, cnt - c0);
    // token ids (clamped for t >= cc; their results are never stored)
    const int tk0 = toklist[c0];
    const int tk1 = toklist[c0 + (1 < cc ? 1 : 0)];
    const int tk2 = toklist[c0 + (2 < cc ? 2 : 0)];
    const int tk3 = toklist[c0 + (3 < cc ? 3 : 0)];

    // x fragments: 12 coalesced 1KB wave-loads (x is L2/L3-hot)
    f32x4 x00 = *(const f32x4*)&X4[(size_t)tk0 * 192 + lane];
    f32x4 x01 = *(const f32x4*)&X4[(size_t)tk0 * 192 + 64 + lane];
    f32x4 x02 = *(const f32x4*)&X4[(size_t)tk0 * 192 + 128 + lane];
    f32x4 x10 = *(const f32x4*)&X4[(size_t)tk1 * 192 + lane];
    f32x4 x11 = *(const f32x4*)&X4[(size_t)tk1 * 192 + 64 + lane];
    f32x4 x12 = *(const f32x4*)&X4[(size_t)tk1 * 192 + 128 + lane];
    f32x4 x20 = *(const f32x4*)&X4[(size_t)tk2 * 192 + lane];
    f32x4 x21 = *(const f32x4*)&X4[(size_t)tk2 * 192 + 64 + lane];
    f32x4 x22 = *(const f32x4*)&X4[(size_t)tk2 * 192 + 128 + lane];
    f32x4 x30 = *(const f32x4*)&X4[(size_t)tk3 * 192 + lane];
    f32x4 x31 = *(const f32x4*)&X4[(size_t)tk3 * 192 + 64 + lane];
    f32x4 x32 = *(const f32x4*)&X4[(size_t)tk3 * 192 + 128 + lane];

    // 2-stage prefetch over the wave's 16 rows (fully unrolled: static regs)
    f32x4 wa0 = *(const f32x4*)&Wc[lane];
    f32x4 wa1 = *(const f32x4*)&Wc[64 + lane];
    f32x4 wa2 = *(const f32x4*)&Wc[128 + lane];
#pragma unroll
    for (int a = 0; a < 16; a++) {
      f32x4 wb0, wb1, wb2;
      if (a < 15) {
        wb0 = *(const f32x4*)&Wc[(a + 1) * 192 + lane];
        wb1 = *(const f32x4*)&Wc[(a + 1) * 192 + 64 + lane];
        wb2 = *(const f32x4*)&Wc[(a + 1) * 192 + 128 + lane];
      }
      float p0 = wa0.x * x00.x + wa0.y * x00.y + wa0.z * x00.z + wa0.w * x00.w
               + wa1.x * x01.x + wa1.y * x01.y + wa1.z * x01.z + wa1.w * x01.w
               + wa2.x * x02.x + wa2.y * x02.y + wa2.z * x02.z + wa2.w * x02.w;
      float p1 = wa0.x * x10.x + wa0.y * x10.y + wa0.z * x10.z + wa0.w * x10.w
               + wa1.x * x11.x + wa1.y * x11.y + wa1.z * x11.z + wa1.w * x11.w
               + wa2.x * x12.x + wa2.y * x12.y + wa2.z * x12.z + wa2.w * x12.w;
      float p2 = wa0.x * x20.x + wa0.y * x20.y + wa0.z * x20.z + wa0.w * x20.w
               + wa1.x * x21.x + wa1.y * x21.y + wa1.z * x21.z + wa1.w * x21.w
               + wa2.x * x22.x + wa2.y * x22.y + wa2.z * x22.z + wa2.w * x22.w;
      float p3 = wa0.x * x30.x + wa0.y * x30.y + wa0.z * x30.z + wa0.w * x30.w
               + wa1.x * x31.x + wa1.y * x31.y + wa1.z * x31.z + wa1.w * x31.w
               + wa2.x * x32.x + wa2.y * x32.y + wa2.z * x32.z + wa2.w * x32.w;

      // merged 4-token butterfly: lane L ends holding token (L&3)'s full sum
      const bool b0 = (lane & 1) != 0;
      float q0 = (b0 ? p1 : p0) + __shfl_xor(b0 ? p0 : p1, 1, 64);
      float q1 = (b0 ? p3 : p2) + __shfl_xor(b0 ? p2 : p3, 1, 64);
      const bool b1 = (lane & 2) != 0;
      float r = (b1 ? q1 : q0) + __shfl_xor(b1 ? q0 : q1, 2, 64);
      r += __shfl_xor(r, 4, 64);
      r += __shfl_xor(r, 8, 64);
      r += __shfl_xor(r, 16, 64);
      r += __shfl_xor(r, 32, 64);

      const int o = w * 16 + a;
      if (lane < cc) {
        y[(size_t)toklist[c0 + lane] * ED + o] = r + eb[e * ED + o];
      }
      wa0 = wb0; wa1 = wb1; wa2 = wb2;
    }
  }
}

// ---- Kernel 4: projection + scale by top_w ----
__global__ __launch_bounds__(256) void proj_kernel(
    const float* __restrict__ y, const float* __restrict__ pw,
    const float* __restrict__ pb, const float* __restrict__ topw,
    float* __restrict__ out) {
  const int b = blockIdx.x;
  const int tid = threadIdx.x;
  __shared__ float4 ys4[8 * 16];
  __shared__ float tw[8];
  if (tid < 128) {
    int t = tid >> 4, q = tid & 15;
    ys4[tid] = ((const float4*)y)[((size_t)b * 8 + t) * 16 + q];
  }
  if (tid < 8) tw[tid] = topw[b * 8 + tid];
  __syncthreads();
  const float4* pw4 = (const float4*)pw;
#pragma unroll
  for (int c = 0; c < 3; c++) {
    int d = c * 256 + tid;
    float4 pwv[16];
#pragma unroll
    for (int q = 0; q < 16; q++) pwv[q] = pw4[(size_t)d * 16 + q];
    float pbv = pb[d];
    for (int t = 0; t < 8; t++) {
      const float4* yv4 = &ys4[t * 16];
      float s = 0.f;
#pragma unroll
      for (int q = 0; q < 16; q++) {
        float4 yv = yv4[q];
        s += pwv[q].x * yv.x + pwv[q].y * yv.y + pwv[q].z * yv.z + pwv[q].w * yv.w;
      }
      out[((size_t)b * 8 + t) * DIM + d] = (s + pbv) * tw[t];
    }
  }
}

// ---------------- launch ----------------
extern "C" void kernel_launch(void* const* d_in, const int* in_sizes, int n_in,
                              void* d_out, int out_size, void* d_ws, size_t ws_size,
                              hipStream_t stream) {
  const float* x      = (const float*)d_in[0];
  const float* noise  = (const float*)d_in[1];
  const float* gate_w = (const float*)d_in[2];
  const float* gate_b = (const float*)d_in[3];
  const float* ew     = (const float*)d_in[4];
  const float* eb     = (const float*)d_in[5];
  const float* pw     = (const float*)d_in[6];
  const float* pb     = (const float*)d_in[7];
  float* out = (float*)d_out;

  char* ws = (char*)d_ws;
  unsigned short* xhi    = (unsigned short*)(ws);                // 6291456
  unsigned short* xlo    = (unsigned short*)(ws + 6291456);      // 6291456
  unsigned short* ghi    = (unsigned short*)(ws + 12582912);     // 2359296
  unsigned short* glo    = (unsigned short*)(ws + 14942208);     // 2359296
  float4*         part_a = (float4*)(ws + 17301504);             // 1572864
  int*            part_i2= (int*)  (ws + 18874368);              //  393216
  float*          y      = (float*)(ws + 19267584);              // 1048576
  float*          topw   = (float*)(ws + 20316160);              //   16384
  int*            idx    = (int*)  (ws + 20332544);              //   16384
  int*            rc_cnt = (int*)  (ws + 20348928);              //     256
  int*            rc_n   = (int*)  (ws + 20349184);              //   16384
  int*            rc_i2  = (int*)  (ws + 20365568);              //   16384

  split_all<<<(NT * DIM / 4 + NE * DIM / 4 + 255) / 256, 256, 0, stream>>>(
      x, gate_w, xhi, xlo, ghi, glo, rc_cnt);
  gate_mfma<<<dim3(NT / 128, NE / 128), 256, 0, stream>>>(
      xhi, xlo, ghi, glo, gate_b, noise, part_a, part_i2);
  finalize<<<NT / 4, 256, 0, stream>>>(part_a, part_i2, topw, idx,
                                       rc_cnt, rc_n, rc_i2);
  recheck<<<64, 256, 0, stream>>>(x, gate_w, gate_b, noise, rc_n, rc_i2, rc_cnt, idx);
  expert_y<<<NE, 256, 0, stream>>>(x, ew, eb, idx, y);
  proj_kernel<<<NT / 8, 256, 0, stream>>>(y, pw, pb, topw, out);
}

// Round 11
// 232.391 us; speedup vs baseline: 1.2734x; 1.0609x over previous
//
#include <hip/hip_runtime.h>
#include <hip/hip_bf16.h>

#define NT 4096      // tokens
#define DIM 768
#define NE 1536      // experts
#define ED 64        // expert dim
#define GAP_THR 8e-3f
#define MAXG 2304    // >= max total groups: (4096 + 3*1536)/4 = 2176

typedef __attribute__((ext_vector_type(8))) short short8v;
typedef __attribute__((ext_vector_type(4))) float f32x4;

__device__ __forceinline__ unsigned short f2bf(float f) {
  unsigned int u = __float_as_uint(f);
  unsigned int r = (u + 0x7fffu + ((u >> 16) & 1u)) >> 16;   // RNE
  return (unsigned short)r;
}
__device__ __forceinline__ float bf2f(unsigned short h) {
  return __uint_as_float(((unsigned int)h) << 16);
}

__device__ __forceinline__ void gload16(const void* g, void* l) {
  __builtin_amdgcn_global_load_lds((const __attribute__((address_space(1))) void*)g,
                                   (__attribute__((address_space(3))) void*)l, 16, 0, 0);
}

__device__ __forceinline__ void top2_merge(float& m1, int& i1, float& m2, int& i2,
                                           float om1, int oi1, float om2, int oi2) {
  if (om1 > m1 || (om1 == m1 && oi1 < i1)) {
    if (m1 > om2 || (m1 == om2 && i1 < oi2)) { m2 = m1; i2 = i1; }
    else { m2 = om2; i2 = oi2; }
    m1 = om1; i1 = oi1;
  } else {
    if (om1 > m2 || (om1 == m2 && oi1 < i2)) { m2 = om1; i2 = oi1; }
  }
}

// ---- Kernel 0: fp32 -> bf16 hi/lo split (x, gate_w); zero rc_cnt + counts ----
__global__ __launch_bounds__(256) void split_all(
    const float* __restrict__ x, const float* __restrict__ gw,
    unsigned short* __restrict__ xhi, unsigned short* __restrict__ xlo,
    unsigned short* __restrict__ ghi, unsigned short* __restrict__ glo,
    int* __restrict__ rc_cnt, int* __restrict__ counts) {
  if (blockIdx.x == 0) {
    for (int j = threadIdx.x; j < NE; j += 256) counts[j] = 0;
    if (threadIdx.x == 0) *rc_cnt = 0;
  }
  const int nx4 = NT * DIM / 4;
  const int ng4 = NE * DIM / 4;
  int i = blockIdx.x * 256 + threadIdx.x;
  const float* src; unsigned short* hi; unsigned short* lo; int j;
  if (i < nx4) { src = x; hi = xhi; lo = xlo; j = i; }
  else { j = i - nx4; if (j >= ng4) return; src = gw; hi = ghi; lo = glo; }
  float4 v = ((const float4*)src)[j];
  unsigned short h0 = f2bf(v.x), h1 = f2bf(v.y), h2 = f2bf(v.z), h3 = f2bf(v.w);
  ((ushort4*)hi)[j] = make_ushort4(h0, h1, h2, h3);
  ((ushort4*)lo)[j] = make_ushort4(f2bf(v.x - bf2f(h0)), f2bf(v.y - bf2f(h1)),
                                   f2bf(v.z - bf2f(h2)), f2bf(v.w - bf2f(h3)));
}

// ---- Kernel 1: gating GEMM (bf16x3 MFMA) + fused partial softmax ----
// 64x128 tile, 4 waves of 64x32 each -> grid 64x12 = 768 blocks = 3/CU exact.
// Partial chunks are 32 cols: 48 chunks per token.
__global__ __launch_bounds__(256) void gate_mfma(
    const unsigned short* __restrict__ xhi, const unsigned short* __restrict__ xlo,
    const unsigned short* __restrict__ ghi, const unsigned short* __restrict__ glo,
    const float* __restrict__ gb, const float* __restrict__ noise,
    float4* __restrict__ part_a, int* __restrict__ part_i2) {
  __shared__ __align__(16) unsigned short sA[2 * 64 * 32];    // hi 0..2047, lo 2048..
  __shared__ __align__(16) unsigned short sB[2 * 128 * 32];   // hi 0..4095, lo 4096..
  const int tid = threadIdx.x;
  const int w = tid >> 6, lane = tid & 63;
  const int bm = blockIdx.x, bn = blockIdx.y;
  const int fr = lane & 15;
  const int fg = lane >> 4;
  const int gsw = fg ^ ((fr >> 1) & 3);

  f32x4 acc[4][2];
#pragma unroll
  for (int i = 0; i < 4; i++)
#pragma unroll
    for (int j = 0; j < 2; j++) acc[i][j] = (f32x4){0.f, 0.f, 0.f, 0.f};

  const size_t arow = (size_t)bm * 64 * DIM;
  const size_t brow = (size_t)bn * 128 * DIM;
  const int rA = tid >> 2;                       // 0..63
  const int sgA = (tid & 3) ^ ((rA >> 1) & 3);   // pre-swizzled source granule
  const int sgB = (tid & 3) ^ ((tid >> 3) & 3);  // same formula, B halves

  for (int kt = 0; kt < DIM; kt += 32) {
    __syncthreads();
    {
      const size_t asrc = arow + (size_t)rA * DIM + kt + sgA * 8;
      gload16(xhi + asrc, &sA[w * 512]);
      gload16(xlo + asrc, &sA[2048 + w * 512]);
#pragma unroll
      for (int h = 0; h < 2; h++) {
        const int r = h * 64 + (tid >> 2);
        const size_t bsrc = brow + (size_t)r * DIM + kt + sgB * 8;
        gload16(ghi + bsrc, &sB[h * 2048 + w * 512]);
        gload16(glo + bsrc, &sB[4096 + h * 2048 + w * 512]);
      }
    }
    __syncthreads();

    short8v ah[4], al[4], bh[2], bl[2];
#pragma unroll
    for (int mf = 0; mf < 4; mf++) {
      int ro = (mf * 16 + fr) * 32 + gsw * 8;
      ah[mf] = *(const short8v*)&sA[ro];
      al[mf] = *(const short8v*)&sA[2048 + ro];
    }
#pragma unroll
    for (int nf = 0; nf < 2; nf++) {
      int ro = (w * 32 + nf * 16 + fr) * 32 + gsw * 8;
      bh[nf] = *(const short8v*)&sB[ro];
      bl[nf] = *(const short8v*)&sB[4096 + ro];
    }
#pragma unroll
    for (int mf = 0; mf < 4; mf++)
#pragma unroll
      for (int nf = 0; nf < 2; nf++) {
        f32x4 c = acc[mf][nf];
        c = __builtin_amdgcn_mfma_f32_16x16x32_bf16(ah[mf], bh[nf], c, 0, 0, 0);
        c = __builtin_amdgcn_mfma_f32_16x16x32_bf16(ah[mf], bl[nf], c, 0, 0, 0);
        c = __builtin_amdgcn_mfma_f32_16x16x32_bf16(al[mf], bh[nf], c, 0, 0, 0);
        acc[mf][nf] = c;
      }
  }

  // fused epilogue: bias + noise, per-token top-2 + expsum over this 32-col chunk
  const int gm0 = bm * 64;
  const int gn0 = bn * 128 + w * 32;
  const int chunk = bn * 4 + w;   // 0..47
  int gcol[2]; float gbv[2];
#pragma unroll
  for (int nf = 0; nf < 2; nf++) { gcol[nf] = gn0 + nf * 16 + fr; gbv[nf] = gb[gcol[nf]]; }
#pragma unroll
  for (int mf = 0; mf < 4; mf++) {
    float sv[2][4];
#pragma unroll
    for (int nf = 0; nf < 2; nf++)
#pragma unroll
      for (int reg = 0; reg < 4; reg++) {
        int gm = gm0 + mf * 16 + fg * 4 + reg;
        sv[nf][reg] = acc[mf][nf][reg] + gbv[nf] + 0.1f * noise[(size_t)gm * NE + gcol[nf]];
      }
#pragma unroll
    for (int reg = 0; reg < 4; reg++) {
      float m1 = sv[0][reg]; int i1 = gcol[0];
      float m2 = -3e38f; int i2 = 0x7fffffff;
      {
        float v = sv[1][reg]; int ii = gcol[1];
        if (v > m1 || (v == m1 && ii < i1)) { m2 = m1; i2 = i1; m1 = v; i1 = ii; }
        else { m2 = v; i2 = ii; }
      }
#pragma unroll
      for (int off = 1; off <= 8; off <<= 1) {
        float om1 = __shfl_xor(m1, off, 64); int oi1 = __shfl_xor(i1, off, 64);
        float om2 = __shfl_xor(m2, off, 64); int oi2 = __shfl_xor(i2, off, 64);
        top2_merge(m1, i1, m2, i2, om1, oi1, om2, oi2);
      }
      float ssum = __expf(sv[0][reg] - m1) + __expf(sv[1][reg] - m1);
#pragma unroll
      for (int off = 1; off <= 8; off <<= 1) ssum += __shfl_xor(ssum, off, 64);
      if (fr == 0) {
        int gm = gm0 + mf * 16 + fg * 4 + reg;
        part_a[(size_t)gm * 48 + chunk] = make_float4(m1, m2, ssum, __int_as_float(i1));
        part_i2[(size_t)gm * 48 + chunk] = i2;
      }
    }
  }
}

// ---- Kernel 2: merge 48 partials/token -> topw, idx, counts, recheck flags ----
__global__ __launch_bounds__(256) void finalize(
    const float4* __restrict__ part_a, const int* __restrict__ part_i2,
    float* __restrict__ topw, int* __restrict__ idx, int* __restrict__ counts,
    int* __restrict__ rc_count, int* __restrict__ rc_n, int* __restrict__ rc_i2) {
  const int wv = threadIdx.x >> 6, lane = threadIdx.x & 63;
  const int n = blockIdx.x * 4 + wv;
  float m1 = -3e38f, m2 = -3e38f, lm1 = -3e38f, lsum = 0.f;
  int i1 = 0x7fffffff, i2 = 0x7fffffff;
  if (lane < 48) {
    float4 pa = part_a[(size_t)n * 48 + lane];
    m1 = pa.x; m2 = pa.y; lsum = pa.z; i1 = __float_as_int(pa.w);
    i2 = part_i2[(size_t)n * 48 + lane];
    lm1 = pa.x;
  }
#pragma unroll
  for (int off = 1; off <= 32; off <<= 1) {
    float om1 = __shfl_xor(m1, off, 64); int oi1 = __shfl_xor(i1, off, 64);
    float om2 = __shfl_xor(m2, off, 64); int oi2 = __shfl_xor(i2, off, 64);
    top2_merge(m1, i1, m2, i2, om1, oi1, om2, oi2);
  }
  float contrib = (lane < 48) ? __expf(lm1 - m1) * lsum : 0.f;
#pragma unroll
  for (int off = 1; off <= 32; off <<= 1) contrib += __shfl_xor(contrib, off, 64);
  if (lane == 0) {
    topw[n] = 1.0f / contrib;
    idx[n] = i1;
    atomicAdd(counts + i1, 1);
    if (m1 - m2 < GAP_THR) {
      int p = atomicAdd(rc_count, 1);
      rc_n[p] = n; rc_i2[p] = i2;
    }
  }
}

// ---- Kernel 2b: fp32 exact recheck of near-tied top-2 (fixes idx + counts) ----
__global__ __launch_bounds__(256) void recheck(
    const float* __restrict__ x, const float* __restrict__ gw,
    const float* __restrict__ gb, const float* __restrict__ noise,
    const int* __restrict__ rc_n, const int* __restrict__ rc_i2,
    const int* __restrict__ rc_count, int* __restrict__ idx, int* __restrict__ counts) {
  __shared__ float r1[4], r2[4];
  const int cnt = *rc_count;
  const int tid = threadIdx.x;
  const int w = tid >> 6, lane = tid & 63;
  for (int t = blockIdx.x; t < cnt; t += gridDim.x) {
    const int n = rc_n[t];
    const int e1 = idx[n], e2 = rc_i2[t];
    const float* xr = x + (size_t)n * DIM;
    const float* w1 = gw + (size_t)e1 * DIM;
    const float* w2 = gw + (size_t)e2 * DIM;
    float p1 = 0.f, p2 = 0.f;
    for (int k = tid; k < DIM; k += 256) {
      float xv = xr[k];
      p1 += xv * w1[k];
      p2 += xv * w2[k];
    }
#pragma unroll
    for (int off = 32; off; off >>= 1) {
      p1 += __shfl_xor(p1, off, 64);
      p2 += __shfl_xor(p2, off, 64);
    }
    if (lane == 0) { r1[w] = p1; r2[w] = p2; }
    __syncthreads();
    if (tid == 0) {
      float s1 = r1[0] + r1[1] + r1[2] + r1[3] + gb[e1] + 0.1f * noise[(size_t)n * NE + e1];
      float s2 = r2[0] + r2[1] + r2[2] + r2[3] + gb[e2] + 0.1f * noise[(size_t)n * NE + e2];
      if (s2 > s1 || (s2 == s1 && e2 < e1)) {
        idx[n] = e2;
        atomicSub(counts + e1, 1);
        atomicAdd(counts + e2, 1);
      }
    }
    __syncthreads();
  }
}

// ---- Kernel 3: dual exclusive scan: token offsets + balanced group queue ----
// Deterministic (no atomics). gdesc[g] = (expert, base_in_sorted, cc<=4).
__global__ __launch_bounds__(256) void scan_offsets(
    const int* __restrict__ counts, int* __restrict__ offs, int* __restrict__ cursor,
    int* __restrict__ gdesc, int* __restrict__ ngroups) {
  __shared__ int part[256];
  __shared__ int part2[256];
  const int t = threadIdx.x;
  int loc[6];
  int s = 0, s2 = 0;
#pragma unroll
  for (int j = 0; j < 6; j++) {
    loc[j] = counts[t * 6 + j];
    s += loc[j];
    s2 += (loc[j] + 3) >> 2;
  }
  part[t] = s; part2[t] = s2;
  __syncthreads();
  for (int d = 1; d < 256; d <<= 1) {
    int v1 = (t >= d) ? part[t - d] : 0;
    int v2 = (t >= d) ? part2[t - d] : 0;
    __syncthreads();
    part[t] += v1; part2[t] += v2;
    __syncthreads();
  }
  int excl = part[t] - s;
  int excl2 = part2[t] - s2;
#pragma unroll
  for (int j = 0; j < 6; j++) {
    const int e = t * 6 + j, c = loc[j];
    offs[e] = excl;
    cursor[e] = excl;
    const int ng = (c + 3) >> 2;
    for (int k = 0; k < ng; k++) {
      gdesc[3 * (excl2 + k)]     = e;
      gdesc[3 * (excl2 + k) + 1] = excl + 4 * k;
      gdesc[3 * (excl2 + k) + 2] = min(4, c - 4 * k);
    }
    excl += c; excl2 += ng;
  }
  if (t == 255) *ngroups = part2[255];
}

// ---- Kernel 4: scatter token ids grouped by expert ----
__global__ __launch_bounds__(256) void scatter_tokens(
    const int* __restrict__ idx, int* __restrict__ cursor, int* __restrict__ sorted) {
  const int n = blockIdx.x * 256 + threadIdx.x;
  int e = idx[n];
  int pos = atomicAdd(cursor + e, 1);
  sorted[pos] = n;
}

// ---- Kernel 5: expert GEMV, one balanced group (<=4 tokens) per block ----
// Coalesced 1KB wave-loads of W, 2-row register prefetch, merged 4-token
// butterfly reduce. No idx scan, no group loop -> perfect load balance.
__global__ __launch_bounds__(256) void expert_y(
    const float* __restrict__ x, const float* __restrict__ ew,
    const float* __restrict__ eb, const int* __restrict__ sorted,
    const int* __restrict__ gdesc, const int* __restrict__ ngroups,
    float* __restrict__ y) {
  const int g = blockIdx.x;
  if (g >= *ngroups) return;
  const int e    = gdesc[3 * g];
  const int base = gdesc[3 * g + 1];
  const int cc   = gdesc[3 * g + 2];
  const int tid = threadIdx.x;
  const int w = tid >> 6, lane = tid & 63;

  const int tk0 = sorted[base];
  const int tk1 = sorted[base + (1 < cc ? 1 : 0)];
  const int tk2 = sorted[base + (2 < cc ? 2 : 0)];
  const int tk3 = sorted[base + (3 < cc ? 3 : 0)];
  const int mytk = (lane == 0) ? tk0 : (lane == 1) ? tk1 : (lane == 2) ? tk2 : tk3;

  const float4* W4 = (const float4*)(ew + (size_t)e * ED * DIM);  // [64][192] f4
  const float4* X4 = (const float4*)x;
  const float4* Wc = W4 + w * 16 * 192;   // wave's 16 contiguous rows

  // x fragments: 12 coalesced 1KB wave-loads (x is L2/L3-hot)
  f32x4 x00 = *(const f32x4*)&X4[(size_t)tk0 * 192 + lane];
  f32x4 x01 = *(const f32x4*)&X4[(size_t)tk0 * 192 + 64 + lane];
  f32x4 x02 = *(const f32x4*)&X4[(size_t)tk0 * 192 + 128 + lane];
  f32x4 x10 = *(const f32x4*)&X4[(size_t)tk1 * 192 + lane];
  f32x4 x11 = *(const f32x4*)&X4[(size_t)tk1 * 192 + 64 + lane];
  f32x4 x12 = *(const f32x4*)&X4[(size_t)tk1 * 192 + 128 + lane];
  f32x4 x20 = *(const f32x4*)&X4[(size_t)tk2 * 192 + lane];
  f32x4 x21 = *(const f32x4*)&X4[(size_t)tk2 * 192 + 64 + lane];
  f32x4 x22 = *(const f32x4*)&X4[(size_t)tk2 * 192 + 128 + lane];
  f32x4 x30 = *(const f32x4*)&X4[(size_t)tk3 * 192 + lane];
  f32x4 x31 = *(const f32x4*)&X4[(size_t)tk3 * 192 + 64 + lane];
  f32x4 x32 = *(const f32x4*)&X4[(size_t)tk3 * 192 + 128 + lane];

  // 2-row-deep register prefetch over the wave's 16 rows (fully unrolled)
  f32x4 wbuf[2][3];
#pragma unroll
  for (int j = 0; j < 3; j++) wbuf[0][j] = *(const f32x4*)&Wc[j * 64 + lane];
#pragma unroll
  for (int j = 0; j < 3; j++) wbuf[1][j] = *(const f32x4*)&Wc[192 + j * 64 + lane];

#pragma unroll
  for (int a = 0; a < 16; a++) {
    const int cur = a & 1;
    f32x4 wa0 = wbuf[cur][0], wa1 = wbuf[cur][1], wa2 = wbuf[cur][2];
    if (a < 14) {
      wbuf[cur][0] = *(const f32x4*)&Wc[(a + 2) * 192 + lane];
      wbuf[cur][1] = *(const f32x4*)&Wc[(a + 2) * 192 + 64 + lane];
      wbuf[cur][2] = *(const f32x4*)&Wc[(a + 2) * 192 + 128 + lane];
    }
    float p0 = wa0.x * x00.x + wa0.y * x00.y + wa0.z * x00.z + wa0.w * x00.w
             + wa1.x * x01.x + wa1.y * x01.y + wa1.z * x01.z + wa1.w * x01.w
             + wa2.x * x02.x + wa2.y * x02.y + wa2.z * x02.z + wa2.w * x02.w;
    float p1 = wa0.x * x10.x + wa0.y * x10.y + wa0.z * x10.z + wa0.w * x10.w
             + wa1.x * x11.x + wa1.y * x11.y + wa1.z * x11.z + wa1.w * x11.w
             + wa2.x * x12.x + wa2.y * x12.y + wa2.z * x12.z + wa2.w * x12.w;
    float p2 = wa0.x * x20.x + wa0.y * x20.y + wa0.z * x20.z + wa0.w * x20.w
             + wa1.x * x21.x + wa1.y * x21.y + wa1.z * x21.z + wa1.w * x21.w
             + wa2.x * x22.x + wa2.y * x22.y + wa2.z * x22.z + wa2.w * x22.w;
    float p3 = wa0.x * x30.x + wa0.y * x30.y + wa0.z * x30.z + wa0.w * x30.w
             + wa1.x * x31.x + wa1.y * x31.y + wa1.z * x31.z + wa1.w * x31.w
             + wa2.x * x32.x + wa2.y * x32.y + wa2.z * x32.z + wa2.w * x32.w;

    // merged 4-token butterfly: lane L (L<4) ends holding token L's full sum
    const bool b0 = (lane & 1) != 0;
    float q0 = (b0 ? p1 : p0) + __shfl_xor(b0 ? p0 : p1, 1, 64);
    float q1 = (b0 ? p3 : p2) + __shfl_xor(b0 ? p2 : p3, 1, 64);
    const bool b1 = (lane & 2) != 0;
    float r = (b1 ? q1 : q0) + __shfl_xor(b1 ? q0 : q1, 2, 64);
    r += __shfl_xor(r, 4, 64);
    r += __shfl_xor(r, 8, 64);
    r += __shfl_xor(r, 16, 64);
    r += __shfl_xor(r, 32, 64);

    const int o = w * 16 + a;
    if (lane < cc) {
      y[(size_t)mytk * ED + o] = r + eb[e * ED + o];
    }
  }
}

// ---- Kernel 6: projection + scale by top_w ----
__global__ __launch_bounds__(256) void proj_kernel(
    const float* __restrict__ y, const float* __restrict__ pw,
    const float* __restrict__ pb, const float* __restrict__ topw,
    float* __restrict__ out) {
  const int b = blockIdx.x;
  const int tid = threadIdx.x;
  __shared__ float4 ys4[8 * 16];
  __shared__ float tw[8];
  if (tid < 128) {
    int t = tid >> 4, q = tid & 15;
    ys4[tid] = ((const float4*)y)[((size_t)b * 8 + t) * 16 + q];
  }
  if (tid < 8) tw[tid] = topw[b * 8 + tid];
  __syncthreads();
  const float4* pw4 = (const float4*)pw;
#pragma unroll
  for (int c = 0; c < 3; c++) {
    int d = c * 256 + tid;
    float4 pwv[16];
#pragma unroll
    for (int q = 0; q < 16; q++) pwv[q] = pw4[(size_t)d * 16 + q];
    float pbv = pb[d];
    for (int t = 0; t < 8; t++) {
      const float4* yv4 = &ys4[t * 16];
      float s = 0.f;
#pragma unroll
      for (int q = 0; q < 16; q++) {
        float4 yv = yv4[q];
        s += pwv[q].x * yv.x + pwv[q].y * yv.y + pwv[q].z * yv.z + pwv[q].w * yv.w;
      }
      out[((size_t)b * 8 + t) * DIM + d] = (s + pbv) * tw[t];
    }
  }
}

// ---------------- launch ----------------
extern "C" void kernel_launch(void* const* d_in, const int* in_sizes, int n_in,
                              void* d_out, int out_size, void* d_ws, size_t ws_size,
                              hipStream_t stream) {
  const float* x      = (const float*)d_in[0];
  const float* noise  = (const float*)d_in[1];
  const float* gate_w = (const float*)d_in[2];
  const float* gate_b = (const float*)d_in[3];
  const float* ew     = (const float*)d_in[4];
  const float* eb     = (const float*)d_in[5];
  const float* pw     = (const float*)d_in[6];
  const float* pb     = (const float*)d_in[7];
  float* out = (float*)d_out;

  char* ws = (char*)d_ws;
  unsigned short* xhi    = (unsigned short*)(ws);                // 6291456
  unsigned short* xlo    = (unsigned short*)(ws + 6291456);      // 6291456
  unsigned short* ghi    = (unsigned short*)(ws + 12582912);     // 2359296
  unsigned short* glo    = (unsigned short*)(ws + 14942208);     // 2359296
  float4*         part_a = (float4*)(ws + 17301504);             // 3145728 (4096x48x16)
  int*            part_i2= (int*)  (ws + 20447232);              //  786432
  float*          y      = (float*)(ws + 21233664);              // 1048576
  float*          topw   = (float*)(ws + 22282240);              //   16384
  int*            idx    = (int*)  (ws + 22298624);              //   16384
  int*            counts = (int*)  (ws + 22315008);              //    6144
  int*            rc_cnt = (int*)  (ws + 22321152);              //     256 (4 used)
  int*            offs   = (int*)  (ws + 22321408);              //    6144
  int*            cursor = (int*)  (ws + 22327552);              //    6144
  int*            sorted = (int*)  (ws + 22333696);              //   16384
  int*            rc_n   = (int*)  (ws + 22350080);              //   16384
  int*            rc_i2  = (int*)  (ws + 22366464);              //   16384
  int*            ngroups= (int*)  (ws + 22382848);              //     256 (4 used)
  int*            gdesc  = (int*)  (ws + 22383104);              //   27648 (2304x3)

  split_all<<<(NT * DIM / 4 + NE * DIM / 4 + 255) / 256, 256, 0, stream>>>(
      x, gate_w, xhi, xlo, ghi, glo, rc_cnt, counts);
  gate_mfma<<<dim3(NT / 64, NE / 128), 256, 0, stream>>>(
      xhi, xlo, ghi, glo, gate_b, noise, part_a, part_i2);
  finalize<<<NT / 4, 256, 0, stream>>>(part_a, part_i2, topw, idx, counts,
                                       rc_cnt, rc_n, rc_i2);
  recheck<<<64, 256, 0, stream>>>(x, gate_w, gate_b, noise, rc_n, rc_i2, rc_cnt,
                                  idx, counts);
  scan_offsets<<<1, 256, 0, stream>>>(counts, offs, cursor, gdesc, ngroups);
  scatter_tokens<<<NT / 256, 256, 0, stream>>>(idx, cursor, sorted);
  expert_y<<<MAXG, 256, 0, stream>>>(x, ew, eb, sorted, gdesc, ngroups, y);
  proj_kernel<<<NT / 8, 256, 0, stream>>>(y, pw, pb, topw, out);
}

// Round 12
// 225.360 us; speedup vs baseline: 1.3131x; 1.0312x over previous
//
#include <hip/hip_runtime.h>
#include <hip/hip_bf16.h>

#define NT 4096      // tokens
#define DIM 768
#define NE 1536      // experts
#define ED 64        // expert dim
#define GAP_THR 8e-3f
#define MAXG 2304    // >= max total groups

typedef __attribute__((ext_vector_type(8))) _Float16 half8v;
typedef __attribute__((ext_vector_type(4))) _Float16 half4v;
typedef __attribute__((ext_vector_type(4))) float f32x4;

__device__ __forceinline__ void gload16(const void* g, void* l) {
  __builtin_amdgcn_global_load_lds((const __attribute__((address_space(1))) void*)g,
                                   (__attribute__((address_space(3))) void*)l, 16, 0, 0);
}

__device__ __forceinline__ void top2_merge(float& m1, int& i1, float& m2, int& i2,
                                           float om1, int oi1, float om2, int oi2) {
  if (om1 > m1 || (om1 == m1 && oi1 < i1)) {
    if (m1 > om2 || (m1 == om2 && i1 < oi2)) { m2 = m1; i2 = i1; }
    else { m2 = om2; i2 = oi2; }
    m1 = om1; i1 = oi1;
  } else {
    if (om1 > m2 || (om1 == m2 && oi1 < i2)) { m2 = om1; i2 = oi1; }
  }
}

// ---- Kernel 0: x -> fp16; gate_w -> fp16 hi + fp16 lo (exact to 2^-21) ----
__global__ __launch_bounds__(256) void split_all(
    const float* __restrict__ x, const float* __restrict__ gw,
    _Float16* __restrict__ xh, _Float16* __restrict__ gh, _Float16* __restrict__ gl,
    int* __restrict__ rc_cnt, int* __restrict__ counts) {
  if (blockIdx.x == 0) {
    for (int j = threadIdx.x; j < NE; j += 256) counts[j] = 0;
    if (threadIdx.x == 0) *rc_cnt = 0;
  }
  const int nx4 = NT * DIM / 4;
  const int ng4 = NE * DIM / 4;
  int i = blockIdx.x * 256 + threadIdx.x;
  if (i < nx4) {
    float4 v = ((const float4*)x)[i];
    half4v hv = {(_Float16)v.x, (_Float16)v.y, (_Float16)v.z, (_Float16)v.w};
    ((half4v*)xh)[i] = hv;
  } else {
    int j = i - nx4;
    if (j >= ng4) return;
    float4 v = ((const float4*)gw)[j];
    half4v hv = {(_Float16)v.x, (_Float16)v.y, (_Float16)v.z, (_Float16)v.w};
    half4v lv = {(_Float16)(v.x - (float)hv[0]), (_Float16)(v.y - (float)hv[1]),
                 (_Float16)(v.z - (float)hv[2]), (_Float16)(v.w - (float)hv[3])};
    ((half4v*)gh)[j] = hv;
    ((half4v*)gl)[j] = lv;
  }
}

// ---- Kernel 1: gating GEMM (fp16 2-pass MFMA) + fused partial softmax ----
// 64x128 tile, BK=32, double-buffered 2-phase: STAGE(next) issued BEFORE the
// current step's compute; __syncthreads' vmcnt(0) drain lands after compute.
// LDS 40 KB -> 4 blocks/CU. 48 partial chunks (32 cols) per token.
__global__ __launch_bounds__(256) void gate_mfma(
    const _Float16* __restrict__ xh, const _Float16* __restrict__ gh,
    const _Float16* __restrict__ gl, const float* __restrict__ gb,
    const float* __restrict__ noise, float4* __restrict__ part_a,
    int* __restrict__ part_i2) {
  __shared__ __align__(16) _Float16 sA[2][64 * 32];     // 4 KB each
  __shared__ __align__(16) _Float16 sBh[2][128 * 32];   // 8 KB each
  __shared__ __align__(16) _Float16 sBl[2][128 * 32];
  const int tid = threadIdx.x;
  const int w = tid >> 6, lane = tid & 63;
  const int bm = blockIdx.x, bn = blockIdx.y;
  const int fr = lane & 15, fg = lane >> 4;
  const int gsw = fg ^ ((fr >> 1) & 3);

  f32x4 acc[4][2];
#pragma unroll
  for (int i = 0; i < 4; i++)
#pragma unroll
    for (int j = 0; j < 2; j++) acc[i][j] = (f32x4){0.f, 0.f, 0.f, 0.f};

  const size_t arow = (size_t)bm * 64 * DIM;
  const size_t brow = (size_t)bn * 128 * DIM;
  const int rA = tid >> 2;
  const int sg = (tid & 3) ^ ((rA >> 1) & 3);   // pre-swizzled source granule
  const int dA = w * 512;                        // wave-uniform LDS dest base

#define STAGE(b, kt) do {                                                     \
    gload16(xh + arow + (size_t)rA * DIM + (kt) + sg * 8, &sA[b][dA]);        \
    gload16(gh + brow + (size_t)rA * DIM + (kt) + sg * 8, &sBh[b][dA]);       \
    gload16(gl + brow + (size_t)rA * DIM + (kt) + sg * 8, &sBl[b][dA]);       \
    gload16(gh + brow + (size_t)(64 + rA) * DIM + (kt) + sg * 8, &sBh[b][2048 + dA]); \
    gload16(gl + brow + (size_t)(64 + rA) * DIM + (kt) + sg * 8, &sBl[b][2048 + dA]); \
  } while (0)

  STAGE(0, 0);
  __syncthreads();

  for (int t = 0; t < 24; t++) {
    const int cur = t & 1;
    if (t < 23) {
      if (cur) STAGE(0, (t + 1) * 32); else STAGE(1, (t + 1) * 32);
    }
    half8v a8[4], b8h[2], b8l[2];
#pragma unroll
    for (int mf = 0; mf < 4; mf++)
      a8[mf] = *(const half8v*)&sA[cur][(mf * 16 + fr) * 32 + gsw * 8];
#pragma unroll
    for (int nf = 0; nf < 2; nf++) {
      int ro = (w * 32 + nf * 16 + fr) * 32 + gsw * 8;
      b8h[nf] = *(const half8v*)&sBh[cur][ro];
      b8l[nf] = *(const half8v*)&sBl[cur][ro];
    }
#pragma unroll
    for (int mf = 0; mf < 4; mf++)
#pragma unroll
      for (int nf = 0; nf < 2; nf++) {
        f32x4 c = acc[mf][nf];
        c = __builtin_amdgcn_mfma_f32_16x16x32_f16(a8[mf], b8h[nf], c, 0, 0, 0);
        c = __builtin_amdgcn_mfma_f32_16x16x32_f16(a8[mf], b8l[nf], c, 0, 0, 0);
        acc[mf][nf] = c;
      }
    __syncthreads();   // drains the prefetch (vmcnt 0) + barrier
  }
#undef STAGE

  // fused epilogue: bias + noise, per-token top-2 + expsum over this 32-col chunk
  const int gm0 = bm * 64;
  const int gn0 = bn * 128 + w * 32;
  const int chunk = bn * 4 + w;   // 0..47
  int gcol[2]; float gbv[2];
#pragma unroll
  for (int nf = 0; nf < 2; nf++) { gcol[nf] = gn0 + nf * 16 + fr; gbv[nf] = gb[gcol[nf]]; }
#pragma unroll
  for (int mf = 0; mf < 4; mf++) {
    float sv[2][4];
#pragma unroll
    for (int nf = 0; nf < 2; nf++)
#pragma unroll
      for (int reg = 0; reg < 4; reg++) {
        int gm = gm0 + mf * 16 + fg * 4 + reg;
        sv[nf][reg] = acc[mf][nf][reg] + gbv[nf] + 0.1f * noise[(size_t)gm * NE + gcol[nf]];
      }
#pragma unroll
    for (int reg = 0; reg < 4; reg++) {
      float m1 = sv[0][reg]; int i1 = gcol[0];
      float m2 = -3e38f; int i2 = 0x7fffffff;
      {
        float v = sv[1][reg]; int ii = gcol[1];
        if (v > m1 || (v == m1 && ii < i1)) { m2 = m1; i2 = i1; m1 = v; i1 = ii; }
        else { m2 = v; i2 = ii; }
      }
#pragma unroll
      for (int off = 1; off <= 8; off <<= 1) {
        float om1 = __shfl_xor(m1, off, 64); int oi1 = __shfl_xor(i1, off, 64);
        float om2 = __shfl_xor(m2, off, 64); int oi2 = __shfl_xor(i2, off, 64);
        top2_merge(m1, i1, m2, i2, om1, oi1, om2, oi2);
      }
      float ssum = __expf(sv[0][reg] - m1) + __expf(sv[1][reg] - m1);
#pragma unroll
      for (int off = 1; off <= 8; off <<= 1) ssum += __shfl_xor(ssum, off, 64);
      if (fr == 0) {
        int gm = gm0 + mf * 16 + fg * 4 + reg;
        part_a[(size_t)gm * 48 + chunk] = make_float4(m1, m2, ssum, __int_as_float(i1));
        part_i2[(size_t)gm * 48 + chunk] = i2;
      }
    }
  }
}

// ---- Kernel 2: merge 48 partials/token -> topw, idx, counts, recheck flags ----
__global__ __launch_bounds__(256) void finalize(
    const float4* __restrict__ part_a, const int* __restrict__ part_i2,
    float* __restrict__ topw, int* __restrict__ idx, int* __restrict__ counts,
    int* __restrict__ rc_count, int* __restrict__ rc_n, int* __restrict__ rc_i2) {
  const int wv = threadIdx.x >> 6, lane = threadIdx.x & 63;
  const int n = blockIdx.x * 4 + wv;
  float m1 = -3e38f, m2 = -3e38f, lm1 = -3e38f, lsum = 0.f;
  int i1 = 0x7fffffff, i2 = 0x7fffffff;
  if (lane < 48) {
    float4 pa = part_a[(size_t)n * 48 + lane];
    m1 = pa.x; m2 = pa.y; lsum = pa.z; i1 = __float_as_int(pa.w);
    i2 = part_i2[(size_t)n * 48 + lane];
    lm1 = pa.x;
  }
#pragma unroll
  for (int off = 1; off <= 32; off <<= 1) {
    float om1 = __shfl_xor(m1, off, 64); int oi1 = __shfl_xor(i1, off, 64);
    float om2 = __shfl_xor(m2, off, 64); int oi2 = __shfl_xor(i2, off, 64);
    top2_merge(m1, i1, m2, i2, om1, oi1, om2, oi2);
  }
  float contrib = (lane < 48) ? __expf(lm1 - m1) * lsum : 0.f;
#pragma unroll
  for (int off = 1; off <= 32; off <<= 1) contrib += __shfl_xor(contrib, off, 64);
  if (lane == 0) {
    topw[n] = 1.0f / contrib;
    idx[n] = i1;
    atomicAdd(counts + i1, 1);
    if (m1 - m2 < GAP_THR) {
      int p = atomicAdd(rc_count, 1);
      rc_n[p] = n; rc_i2[p] = i2;
    }
  }
}

// ---- Kernel 2b: fp32 exact recheck of near-tied top-2 (fixes idx + counts) ----
__global__ __launch_bounds__(256) void recheck(
    const float* __restrict__ x, const float* __restrict__ gw,
    const float* __restrict__ gb, const float* __restrict__ noise,
    const int* __restrict__ rc_n, const int* __restrict__ rc_i2,
    const int* __restrict__ rc_count, int* __restrict__ idx, int* __restrict__ counts) {
  __shared__ float r1[4], r2[4];
  const int cnt = *rc_count;
  const int tid = threadIdx.x;
  const int w = tid >> 6, lane = tid & 63;
  for (int t = blockIdx.x; t < cnt; t += gridDim.x) {
    const int n = rc_n[t];
    const int e1 = idx[n], e2 = rc_i2[t];
    const float* xr = x + (size_t)n * DIM;
    const float* w1 = gw + (size_t)e1 * DIM;
    const float* w2 = gw + (size_t)e2 * DIM;
    float p1 = 0.f, p2 = 0.f;
    for (int k = tid; k < DIM; k += 256) {
      float xv = xr[k];
      p1 += xv * w1[k];
      p2 += xv * w2[k];
    }
#pragma unroll
    for (int off = 32; off; off >>= 1) {
      p1 += __shfl_xor(p1, off, 64);
      p2 += __shfl_xor(p2, off, 64);
    }
    if (lane == 0) { r1[w] = p1; r2[w] = p2; }
    __syncthreads();
    if (tid == 0) {
      float s1 = r1[0] + r1[1] + r1[2] + r1[3] + gb[e1] + 0.1f * noise[(size_t)n * NE + e1];
      float s2 = r2[0] + r2[1] + r2[2] + r2[3] + gb[e2] + 0.1f * noise[(size_t)n * NE + e2];
      if (s2 > s1 || (s2 == s1 && e2 < e1)) {
        idx[n] = e2;
        atomicSub(counts + e1, 1);
        atomicAdd(counts + e2, 1);
      }
    }
    __syncthreads();
  }
}

// ---- Kernel 3: fused scan + group-queue build + scatter (one block) ----
__global__ __launch_bounds__(256) void sortscan(
    const int* __restrict__ counts, const int* __restrict__ idx,
    int* __restrict__ sorted, int* __restrict__ gdesc, int* __restrict__ ngroups) {
  __shared__ int part[256];
  __shared__ int part2[256];
  __shared__ int lcur[NE];
  const int t = threadIdx.x;
  int loc[6];
  int s = 0, s2 = 0;
#pragma unroll
  for (int j = 0; j < 6; j++) {
    loc[j] = counts[t * 6 + j];
    s += loc[j];
    s2 += (loc[j] + 3) >> 2;
  }
  part[t] = s; part2[t] = s2;
  __syncthreads();
  for (int d = 1; d < 256; d <<= 1) {
    int v1 = (t >= d) ? part[t - d] : 0;
    int v2 = (t >= d) ? part2[t - d] : 0;
    __syncthreads();
    part[t] += v1; part2[t] += v2;
    __syncthreads();
  }
  int excl = part[t] - s;
  int excl2 = part2[t] - s2;
#pragma unroll
  for (int j = 0; j < 6; j++) {
    const int e = t * 6 + j, c = loc[j];
    lcur[e] = excl;
    const int ng = (c + 3) >> 2;
    for (int k = 0; k < ng; k++) {
      gdesc[3 * (excl2 + k)]     = e;
      gdesc[3 * (excl2 + k) + 1] = excl + 4 * k;
      gdesc[3 * (excl2 + k) + 2] = min(4, c - 4 * k);
    }
    excl += c; excl2 += ng;
  }
  if (t == 255) *ngroups = part2[255];
  __syncthreads();
  for (int n = t; n < NT; n += 256) {
    int e = idx[n];
    int pos = atomicAdd(&lcur[e], 1);
    sorted[pos] = n;
  }
}

// ---- Kernel 4: expert GEMV, one balanced group (<=4 tokens) per block ----
__global__ __launch_bounds__(256) void expert_y(
    const float* __restrict__ x, const float* __restrict__ ew,
    const float* __restrict__ eb, const int* __restrict__ sorted,
    const int* __restrict__ gdesc, const int* __restrict__ ngroups,
    float* __restrict__ y) {
  const int g = blockIdx.x;
  if (g >= *ngroups) return;
  const int e    = gdesc[3 * g];
  const int base = gdesc[3 * g + 1];
  const int cc   = gdesc[3 * g + 2];
  const int tid = threadIdx.x;
  const int w = tid >> 6, lane = tid & 63;

  const int tk0 = sorted[base];
  const int tk1 = sorted[base + (1 < cc ? 1 : 0)];
  const int tk2 = sorted[base + (2 < cc ? 2 : 0)];
  const int tk3 = sorted[base + (3 < cc ? 3 : 0)];
  const int mytk = (lane == 0) ? tk0 : (lane == 1) ? tk1 : (lane == 2) ? tk2 : tk3;

  const float4* W4 = (const float4*)(ew + (size_t)e * ED * DIM);
  const float4* X4 = (const float4*)x;
  const float4* Wc = W4 + w * 16 * 192;

  f32x4 x00 = *(const f32x4*)&X4[(size_t)tk0 * 192 + lane];
  f32x4 x01 = *(const f32x4*)&X4[(size_t)tk0 * 192 + 64 + lane];
  f32x4 x02 = *(const f32x4*)&X4[(size_t)tk0 * 192 + 128 + lane];
  f32x4 x10 = *(const f32x4*)&X4[(size_t)tk1 * 192 + lane];
  f32x4 x11 = *(const f32x4*)&X4[(size_t)tk1 * 192 + 64 + lane];
  f32x4 x12 = *(const f32x4*)&X4[(size_t)tk1 * 192 + 128 + lane];
  f32x4 x20 = *(const f32x4*)&X4[(size_t)tk2 * 192 + lane];
  f32x4 x21 = *(const f32x4*)&X4[(size_t)tk2 * 192 + 64 + lane];
  f32x4 x22 = *(const f32x4*)&X4[(size_t)tk2 * 192 + 128 + lane];
  f32x4 x30 = *(const f32x4*)&X4[(size_t)tk3 * 192 + lane];
  f32x4 x31 = *(const f32x4*)&X4[(size_t)tk3 * 192 + 64 + lane];
  f32x4 x32 = *(const f32x4*)&X4[(size_t)tk3 * 192 + 128 + lane];

  f32x4 wbuf[2][3];
#pragma unroll
  for (int j = 0; j < 3; j++) wbuf[0][j] = *(const f32x4*)&Wc[j * 64 + lane];
#pragma unroll
  for (int j = 0; j < 3; j++) wbuf[1][j] = *(const f32x4*)&Wc[192 + j * 64 + lane];

#pragma unroll
  for (int a = 0; a < 16; a++) {
    const int cur = a & 1;
    f32x4 wa0 = wbuf[cur][0], wa1 = wbuf[cur][1], wa2 = wbuf[cur][2];
    if (a < 14) {
      wbuf[cur][0] = *(const f32x4*)&Wc[(a + 2) * 192 + lane];
      wbuf[cur][1] = *(const f32x4*)&Wc[(a + 2) * 192 + 64 + lane];
      wbuf[cur][2] = *(const f32x4*)&Wc[(a + 2) * 192 + 128 + lane];
    }
    float p0 = wa0.x * x00.x + wa0.y * x00.y + wa0.z * x00.z + wa0.w * x00.w
             + wa1.x * x01.x + wa1.y * x01.y + wa1.z * x01.z + wa1.w * x01.w
             + wa2.x * x02.x + wa2.y * x02.y + wa2.z * x02.z + wa2.w * x02.w;
    float p1 = wa0.x * x10.x + wa0.y * x10.y + wa0.z * x10.z + wa0.w * x10.w
             + wa1.x * x11.x + wa1.y * x11.y + wa1.z * x11.z + wa1.w * x11.w
             + wa2.x * x12.x + wa2.y * x12.y + wa2.z * x12.z + wa2.w * x12.w;
    float p2 = wa0.x * x20.x + wa0.y * x20.y + wa0.z * x20.z + wa0.w * x20.w
             + wa1.x * x21.x + wa1.y * x21.y + wa1.z * x21.z + wa1.w * x21.w
             + wa2.x * x22.x + wa2.y * x22.y + wa2.z * x22.z + wa2.w * x22.w;
    float p3 = wa0.x * x30.x + wa0.y * x30.y + wa0.z * x30.z + wa0.w * x30.w
             + wa1.x * x31.x + wa1.y * x31.y + wa1.z * x31.z + wa1.w * x31.w
             + wa2.x * x32.x + wa2.y * x32.y + wa2.z * x32.z + wa2.w * x32.w;

    const bool b0 = (lane & 1) != 0;
    float q0 = (b0 ? p1 : p0) + __shfl_xor(b0 ? p0 : p1, 1, 64);
    float q1 = (b0 ? p3 : p2) + __shfl_xor(b0 ? p2 : p3, 1, 64);
    const bool b1 = (lane & 2) != 0;
    float r = (b1 ? q1 : q0) + __shfl_xor(b1 ? q0 : q1, 2, 64);
    r += __shfl_xor(r, 4, 64);
    r += __shfl_xor(r, 8, 64);
    r += __shfl_xor(r, 16, 64);
    r += __shfl_xor(r, 32, 64);

    const int o = w * 16 + a;
    if (lane < cc) {
      y[(size_t)mytk * ED + o] = r + eb[e * ED + o];
    }
  }
}

// ---- Kernel 5: projection + scale by top_w ----
__global__ __launch_bounds__(256) void proj_kernel(
    const float* __restrict__ y, const float* __restrict__ pw,
    const float* __restrict__ pb, const float* __restrict__ topw,
    float* __restrict__ out) {
  const int b = blockIdx.x;
  const int tid = threadIdx.x;
  __shared__ float4 ys4[8 * 16];
  __shared__ float tw[8];
  if (tid < 128) {
    int t = tid >> 4, q = tid & 15;
    ys4[tid] = ((const float4*)y)[((size_t)b * 8 + t) * 16 + q];
  }
  if (tid < 8) tw[tid] = topw[b * 8 + tid];
  __syncthreads();
  const float4* pw4 = (const float4*)pw;
#pragma unroll
  for (int c = 0; c < 3; c++) {
    int d = c * 256 + tid;
    float4 pwv[16];
#pragma unroll
    for (int q = 0; q < 16; q++) pwv[q] = pw4[(size_t)d * 16 + q];
    float pbv = pb[d];
    for (int t = 0; t < 8; t++) {
      const float4* yv4 = &ys4[t * 16];
      float s = 0.f;
#pragma unroll
      for (int q = 0; q < 16; q++) {
        float4 yv = yv4[q];
        s += pwv[q].x * yv.x + pwv[q].y * yv.y + pwv[q].z * yv.z + pwv[q].w * yv.w;
      }
      out[((size_t)b * 8 + t) * DIM + d] = (s + pbv) * tw[t];
    }
  }
}

// ---------------- launch ----------------
extern "C" void kernel_launch(void* const* d_in, const int* in_sizes, int n_in,
                              void* d_out, int out_size, void* d_ws, size_t ws_size,
                              hipStream_t stream) {
  const float* x      = (const float*)d_in[0];
  const float* noise  = (const float*)d_in[1];
  const float* gate_w = (const float*)d_in[2];
  const float* gate_b = (const float*)d_in[3];
  const float* ew     = (const float*)d_in[4];
  const float* eb     = (const float*)d_in[5];
  const float* pw     = (const float*)d_in[6];
  const float* pb     = (const float*)d_in[7];
  float* out = (float*)d_out;

  char* ws = (char*)d_ws;
  _Float16* xh     = (_Float16*)(ws);                 // 6291456
  _Float16* gh     = (_Float16*)(ws + 6291456);       // 2359296
  _Float16* gl     = (_Float16*)(ws + 8650752);       // 2359296
  float4*   part_a = (float4*)(ws + 11010048);        // 3145728
  int*      part_i2= (int*)   (ws + 14155776);        //  786432
  float*    y      = (float*)  (ws + 14942208);       // 1048576
  float*    topw   = (float*)  (ws + 15990784);       //   16384
  int*      idx    = (int*)    (ws + 16007168);       //   16384
  int*      counts = (int*)    (ws + 16023552);       //    6144
  int*      rc_cnt = (int*)    (ws + 16029696);       //     256
  int*      sorted = (int*)    (ws + 16029952);       //   16384
  int*      rc_n   = (int*)    (ws + 16046336);       //   16384
  int*      rc_i2  = (int*)    (ws + 16062720);       //   16384
  int*      ngroups= (int*)    (ws + 16079104);       //     256
  int*      gdesc  = (int*)    (ws + 16079360);       //   27648

  split_all<<<(NT * DIM / 4 + NE * DIM / 4 + 255) / 256, 256, 0, stream>>>(
      x, gate_w, xh, gh, gl, rc_cnt, counts);
  gate_mfma<<<dim3(NT / 64, NE / 128), 256, 0, stream>>>(
      xh, gh, gl, gate_b, noise, part_a, part_i2);
  finalize<<<NT / 4, 256, 0, stream>>>(part_a, part_i2, topw, idx, counts,
                                       rc_cnt, rc_n, rc_i2);
  recheck<<<64, 256, 0, stream>>>(x, gate_w, gate_b, noise, rc_n, rc_i2, rc_cnt,
                                  idx, counts);
  sortscan<<<1, 256, 0, stream>>>(counts, idx, sorted, gdesc, ngroups);
  expert_y<<<MAXG, 256, 0, stream>>>(x, ew, eb, sorted, gdesc, ngroups, y);
  proj_kernel<<<NT / 8, 256, 0, stream>>>(y, pw, pb, topw, out);
}